// Round 4
// baseline (10119.350 us; speedup 1.0000x reference)
//
#include <hip/hip_runtime.h>
#include <stdint.h>

typedef __bf16 bf16x8 __attribute__((ext_vector_type(8)));
typedef float f32x16 __attribute__((ext_vector_type(16)));
typedef unsigned long long u64;

struct Params {
  const float *x, *s_in, *Wf, *bf, *Wo, *bo, *Wi, *bi, *Wg, *bg;
  const float *Wsi, *bsi, *Wsg, *bsg;
  const float *eWih, *eWhh, *ebih, *ebhh;
  const float *dWih0, *dWhh0, *dbih0, *dbhh0;
  const float *dWih1, *dWhh1, *dbih1, *dbhh1;
  const float *fcW, *fcb;
  float* out;
  unsigned* ctrl;
  unsigned short *wpea_h, *wpea_l, *wpenc_h, *wpenc_l;
  unsigned short *wpd0_h, *wpd0_l, *wpd1_h, *wpd1_l;
  unsigned short *xp;
  float *si_v, *sg_v, *cbea, *cbenc, *cbd0, *cbd1, *w0v, *fcw, *pred;
  unsigned short *henc, *hA, *hB, *hseq;
};

#define SLOT 131072   // elems per h slot: [plane2][s256][u256]
#define XP_TOTAL 5980160   // 365 * 2 * 256 * 32  (round-2/3 bug: was 5979136 -> tail read si_v garbage)

__device__ __forceinline__ unsigned short f2bf(float f){
  unsigned u = __builtin_bit_cast(unsigned, f);
  u += 0x7FFFu + ((u >> 16) & 1u);
  return (unsigned short)(u >> 16);
}
__device__ __forceinline__ float bf2f(unsigned short h){
  return __builtin_bit_cast(float, ((unsigned)h) << 16);
}
__device__ __forceinline__ float sigm(float v){ return 1.0f / (1.0f + __expf(-v)); }
__device__ __forceinline__ float tanh_f(float v){
  float a = fabsf(v);
  float e = __expf(-2.0f * a);
  float t = (1.0f - e) / (1.0f + e);
  return __builtin_copysignf(t, v);
}

__device__ __forceinline__ u64 mall_ld(const unsigned short* p){
  return __hip_atomic_load((const u64*)p, __ATOMIC_RELAXED, __HIP_MEMORY_SCOPE_SYSTEM);
}
// Cross-block data publish via RETURNING atomic RMW: performed at the MALL
// before vmcnt-ack, so gbar's chain (vmcnt drain -> counter -> flag -> remote
// load) cannot let the flag overtake the data.
__device__ __forceinline__ void mall_publish(unsigned short* p, u64 v){
  u64 old = __hip_atomic_exchange((u64*)p, v, __ATOMIC_RELAXED, __HIP_MEMORY_SCOPE_SYSTEM);
  asm volatile("" :: "v"(old));   // sink: force the returning (sc0) form
}

extern "C" __global__ void __launch_bounds__(256, 1) ea_lstm_fused(Params P){
  __shared__ __align__(16) unsigned short aLds[32768];   // up to [pl2][kp64][s32][j8]
  __shared__ __align__(16) float gdump[4352];            // [kh2][s32][col64 +4 pad]
  __shared__ __align__(16) float redl[128];              // [u4][s32]

  const int tid = threadIdx.x;
  const int blk = blockIdx.x;
  const int sgp = blk >> 4;   // sample group 0..7 (32 samples each)
  const int cbk = blk & 15;   // column block 0..15 (64 gate cols = 16 units)
  const int lane = tid & 63;
  const int wv = tid >> 6;
  const int gtid = blk * 256 + tid;
  const int kgl = lane >> 5;
  const int aln = lane & 31;

  // ---------------- precompute (all 128 blocks) ----------------
  {
    for (int e = gtid; e < 294912; e += 32768){           // EA weights [288 x 1024]
      int j = e & 7, kg = (e >> 3) & 1, col = (e >> 4) & 1023, kt = e >> 14;
      int k = kt * 16 + kg * 8 + j;
      int u = col >> 2, g = col & 3;
      const float* Wp = (g == 0) ? P.Wf : (g == 1) ? P.Wo : (g == 2) ? P.Wi : P.Wg;
      float w = Wp[u * 288 + k];
      unsigned short hi = f2bf(w);
      P.wpea_h[e] = hi; P.wpea_l[e] = f2bf(w - bf2f(hi));
    }
    for (int e = gtid; e < 524288; e += 32768){           // enc [512 x 1024]
      int j = e & 7, kg = (e >> 3) & 1, col = (e >> 4) & 1023, kt = e >> 14;
      int k = kt * 16 + kg * 8 + j;
      int u = col >> 2, g = col & 3, row = g * 256 + u;
      float w = (k < 256) ? P.eWih[row * 256 + k] : P.eWhh[row * 256 + (k - 256)];
      unsigned short hi = f2bf(w);
      P.wpenc_h[e] = hi; P.wpenc_l[e] = f2bf(w - bf2f(hi));
    }
    for (int e = gtid; e < 262144; e += 32768){           // dec0 [256 x 1024]
      int j = e & 7, kg = (e >> 3) & 1, col = (e >> 4) & 1023, kt = e >> 14;
      int k = kt * 16 + kg * 8 + j;
      int u = col >> 2, g = col & 3, row = g * 256 + u;
      float w = P.dWhh0[row * 256 + k];
      unsigned short hi = f2bf(w);
      P.wpd0_h[e] = hi; P.wpd0_l[e] = f2bf(w - bf2f(hi));
    }
    for (int e = gtid; e < 524288; e += 32768){           // dec1 [512 x 1024]
      int j = e & 7, kg = (e >> 3) & 1, col = (e >> 4) & 1023, kt = e >> 14;
      int k = kt * 16 + kg * 8 + j;
      int u = col >> 2, g = col & 3, row = g * 256 + u;
      float w = (k < 256) ? P.dWih1[row * 256 + k] : P.dWhh1[row * 256 + (k - 256)];
      unsigned short hi = f2bf(w);
      P.wpd1_h[e] = hi; P.wpd1_l[e] = f2bf(w - bf2f(hi));
    }
    for (int e = gtid; e < XP_TOTAL; e += 32768){         // x -> [t][pl2][s256][f32]
      int f = e & 31, sl = (e >> 5) & 255, pl = (e >> 13) & 1, t = e >> 14;
      float w = P.x[((size_t)sl * 365 + t) * 32 + f];
      unsigned short hi = f2bf(w);
      P.xp[e] = pl ? f2bf(w - bf2f(hi)) : hi;
    }
    for (int e = gtid; e < 65536; e += 32768){            // si/sg statics (incl. bi/bg)
      int u = e & 255, b = e >> 8;
      float ai = P.bsi[u] + P.bi[u];
      float ag = P.bsg[u] + P.bg[u];
      for (int k = 0; k < 27; ++k){
        float sv = P.s_in[b * 27 + k];
        ai += sv * P.Wsi[u * 27 + k];
        ag += sv * P.Wsg[u * 27 + k];
      }
      P.si_v[b * 256 + u] = ai;
      P.sg_v[b * 256 + u] = ag;
    }
    for (int e = gtid; e < 1024; e += 32768){             // col biases / vectors
      int u = e >> 2, g = e & 3, row = g * 256 + u;
      P.cbea[e] = (g == 0) ? P.bf[u] : (g == 1) ? P.bo[u] : 0.0f;
      P.cbenc[e] = P.ebih[row] + P.ebhh[row];
      P.cbd0[e]  = P.dbih0[row] + P.dbhh0[row];
      P.cbd1[e]  = P.dbih1[row] + P.dbhh1[row];
      P.w0v[e]   = P.dWih0[row];
      if (e < 256) P.fcw[e] = P.fcW[e];
    }
    for (int e = gtid; e < 6144; e += 32768) P.pred[e] = P.fcb[0];
  }

  // one-time full barrier (fenced ACQ_REL: wbl2 flushes precompute stores,
  // inv drops stale lines — acceptable once)
  __syncthreads();
  if (tid == 0){
    unsigned n = __hip_atomic_fetch_add(P.ctrl, 1u, __ATOMIC_ACQ_REL, __HIP_MEMORY_SCOPE_AGENT) + 1u;
    if (n == 128u) __hip_atomic_store(P.ctrl + 16, 1u, __ATOMIC_RELEASE, __HIP_MEMORY_SCOPE_AGENT);
    else while (__hip_atomic_load(P.ctrl + 16, __ATOMIC_ACQUIRE, __HIP_MEMORY_SCOPE_AGENT) < 1u)
      __builtin_amdgcn_s_sleep(2);
  }
  __syncthreads();

  // ---------------- group barrier: relaxed atomics, no cache maintenance ----------------
  unsigned* gctr  = P.ctrl + 32 + 32 * sgp;
  unsigned* gflag = gctr + 16;
  unsigned gphase = 0;

  auto gbar = [&](){
    ++gphase;
    __syncthreads();   // drains each wave's vmcnt (incl. returning swaps -> data at MALL)
    if (tid == 0){
      unsigned n = __hip_atomic_fetch_add(gctr, 1u, __ATOMIC_RELAXED, __HIP_MEMORY_SCOPE_AGENT) + 1u;
      if (n == 16u * gphase)
        __hip_atomic_store(gflag, gphase, __ATOMIC_RELAXED, __HIP_MEMORY_SCOPE_AGENT);
      else while (__hip_atomic_load(gflag, __ATOMIC_RELAXED, __HIP_MEMORY_SCOPE_AGENT) < gphase)
        __builtin_amdgcn_s_sleep(1);
      __builtin_amdgcn_fence(__ATOMIC_ACQUIRE, "workgroup");
    }
    __syncthreads();
  };

  // ---------------- staging: global(MALL) -> LDS A-tile ----------------
  auto stageA = [&](int kpT, const unsigned short* xb,
                    const unsigned short* sA, const unsigned short* sB, int kpB0){
    for (int uidx = tid; uidx < kpT * 128; uidx += 256){
      int jh = uidx & 1, s = (uidx >> 1) & 31, rest = uidx >> 6;
      int pl = (rest >= kpT) ? 1 : 0;
      int kp = rest - pl * kpT;
      u64 v = 0;
      if (xb && kp < 4){
        v = mall_ld(xb + (size_t)pl * 8192 + (size_t)(sgp * 32 + s) * 32 + kp * 8 + jh * 4);
      } else {
        int hk = kp - (xb ? 4 : 0);
        const unsigned short* sl = sA;
        if (sB && hk >= kpB0){ sl = sB; hk -= kpB0; }
        if (sl) v = mall_ld(sl + (size_t)pl * 65536 + (size_t)(sgp * 32 + s) * 256 + hk * 8 + jh * 4);
      }
      *(u64*)&aLds[((pl * kpT + kp) * 32 + s) * 8 + jh * 4] = v;
    }
  };

  // ---------------- MFMA: wave = (col-tile, K-half) ----------------
  auto runMfma = [&](int kpT, const unsigned short* wh, const unsigned short* wl) -> f32x16 {
    f32x16 acc;
    #pragma unroll
    for (int r = 0; r < 16; ++r) acc[r] = 0.0f;
    const int nh = kpT >> 2;
    const int kt0 = (wv >> 1) * nh;
    const int colg = cbk * 64 + (wv & 1) * 32 + aln;
    #pragma unroll 4
    for (int i = 0; i < nh; ++i){
      int kt = kt0 + i;
      int p = 2 * kt + kgl;
      bf16x8 ahi = __builtin_bit_cast(bf16x8, *(const uint4*)&aLds[((0 * kpT + p) * 32 + aln) * 8]);
      bf16x8 alo = __builtin_bit_cast(bf16x8, *(const uint4*)&aLds[((1 * kpT + p) * 32 + aln) * 8]);
      size_t be = ((size_t)kt * 1024 + colg) * 16 + (size_t)kgl * 8;
      bf16x8 bhi = __builtin_bit_cast(bf16x8, *(const uint4*)(wh + be));
      bf16x8 blo = __builtin_bit_cast(bf16x8, *(const uint4*)(wl + be));
      acc = __builtin_amdgcn_mfma_f32_32x32x16_bf16(alo, bhi, acc, 0, 0, 0);
      acc = __builtin_amdgcn_mfma_f32_32x32x16_bf16(ahi, blo, acc, 0, 0, 0);
      acc = __builtin_amdgcn_mfma_f32_32x32x16_bf16(ahi, bhi, acc, 0, 0, 0);
    }
    return acc;
  };

  auto dump = [&](const f32x16& acc){
    const int kh = wv >> 1, tl = wv & 1;
    #pragma unroll
    for (int r = 0; r < 16; ++r){
      int row = (r & 3) + 8 * (r >> 2) + 4 * kgl;    // verified C/D layout (sample)
      gdump[(kh * 32 + row) * 68 + tl * 32 + aln] = acc[r];
    }
  };

  const int s_loc = tid & 31;
  const int u4 = tid >> 5;
  const int s_g = sgp * 32 + s_loc;
  const int u_g0 = cbk * 16 + u4 * 4;
  const bool ew = (tid < 128);

  auto write_h4 = [&](unsigned short* slot, const float* h){
    u64 hi = 0, lo = 0;
    #pragma unroll
    for (int i = 0; i < 4; ++i){
      unsigned short hb = f2bf(h[i]);
      hi |= (u64)hb << (16 * i);
      lo |= (u64)f2bf(h[i] - bf2f(hb)) << (16 * i);
    }
    size_t o = (size_t)s_g * 256 + u_g0;
    mall_publish(slot + o, hi);
    mall_publish(slot + 65536 + o, lo);
  };

  float cst[4] = {0.f, 0.f, 0.f, 0.f};

  // ---------------- EA phase ----------------
  {
    float cbr[4][4], sir[4], sgr[4];
    if (ew){
      #pragma unroll
      for (int i = 0; i < 4; ++i){
        float4 cb = *(const float4*)&P.cbea[4 * (u_g0 + i)];
        cbr[i][0] = cb.x; cbr[i][1] = cb.y; cbr[i][2] = cb.z; cbr[i][3] = cb.w;
        sir[i] = P.si_v[s_g * 256 + u_g0 + i];
        sgr[i] = P.sg_v[s_g * 256 + u_g0 + i];
      }
    }
    for (int t = 0; t < 365; ++t){
      const unsigned short* hslot = t ? P.hseq + (size_t)(t - 1) * SLOT : nullptr;
      stageA(36, P.xp + (size_t)t * 16384, hslot, nullptr, 0);
      __syncthreads();
      f32x16 acc = runMfma(36, P.wpea_h, P.wpea_l);
      dump(acc);
      __syncthreads();
      if (ew){
        unsigned short* oslot = P.hseq + (size_t)t * SLOT;
        float h4[4];
        #pragma unroll
        for (int i = 0; i < 4; ++i){
          int c0 = u4 * 16 + 4 * i;
          float4 a = *(const float4*)&gdump[(0 * 32 + s_loc) * 68 + c0];
          float4 b = *(const float4*)&gdump[(1 * 32 + s_loc) * 68 + c0];
          float f = sigm(a.x + b.x + cbr[i][0]);
          float o = sigm(a.y + b.y + cbr[i][1]);
          float ii = sigm(a.z + b.z + sir[i]);
          float g = tanh_f(a.w + b.w + sgr[i]);
          float c = f * cst[i] + ii * g;
          cst[i] = c;
          h4[i] = o * tanh_f(c);
        }
        write_h4(oslot, h4);
      }
      gbar();
    }
  }

  // ---------------- encoder phase ----------------
  {
    float cbr[4][4];
    if (ew){
      #pragma unroll
      for (int i = 0; i < 4; ++i){
        float4 cb = *(const float4*)&P.cbenc[4 * (u_g0 + i)];
        cbr[i][0] = cb.x; cbr[i][1] = cb.y; cbr[i][2] = cb.z; cbr[i][3] = cb.w;
      }
    }
    for (int t = 0; t < 365; ++t){
      const unsigned short* hprev = t ? P.henc + (size_t)((t - 1) & 1) * SLOT
                                      : P.hseq + (size_t)364 * SLOT;
      stageA(64, nullptr, P.hseq + (size_t)t * SLOT, hprev, 32);
      __syncthreads();
      f32x16 acc = runMfma(64, P.wpenc_h, P.wpenc_l);
      dump(acc);
      __syncthreads();
      if (ew){
        unsigned short* oslot = P.henc + (size_t)(t & 1) * SLOT;
        float h4[4];
        #pragma unroll
        for (int i = 0; i < 4; ++i){
          int c0 = u4 * 16 + 4 * i;
          float4 a = *(const float4*)&gdump[(0 * 32 + s_loc) * 68 + c0];
          float4 b = *(const float4*)&gdump[(1 * 32 + s_loc) * 68 + c0];
          float ii = sigm(a.x + b.x + cbr[i][0]);
          float f = sigm(a.y + b.y + cbr[i][1]);
          float g = tanh_f(a.z + b.z + cbr[i][2]);
          float o = sigm(a.w + b.w + cbr[i][3]);
          float c = f * cst[i] + ii * g;
          cst[i] = c;
          h4[i] = o * tanh_f(c);
        }
        write_h4(oslot, h4);
      }
      gbar();
    }
  }

  // ---------------- decoder phase ----------------
  {
    float cb0r[4][4], cb1r[4][4], w0r[4][4], fcwr[4];
    if (ew){
      #pragma unroll
      for (int i = 0; i < 4; ++i){
        float4 c0v = *(const float4*)&P.cbd0[4 * (u_g0 + i)];
        float4 c1v = *(const float4*)&P.cbd1[4 * (u_g0 + i)];
        float4 w0v4 = *(const float4*)&P.w0v[4 * (u_g0 + i)];
        cb0r[i][0] = c0v.x; cb0r[i][1] = c0v.y; cb0r[i][2] = c0v.z; cb0r[i][3] = c0v.w;
        cb1r[i][0] = c1v.x; cb1r[i][1] = c1v.y; cb1r[i][2] = c1v.z; cb1r[i][3] = c1v.w;
        w0r[i][0] = w0v4.x; w0r[i][1] = w0v4.y; w0r[i][2] = w0v4.z; w0r[i][3] = w0v4.w;
        fcwr[i] = P.fcw[u_g0 + i];
      }
    }
    float cA[4], cB[4];
    #pragma unroll
    for (int i = 0; i < 4; ++i){ cA[i] = cst[i]; cB[i] = cst[i]; }

    for (int t = 0; t < 24; ++t){
      // ---- cell 0 (K=256: hA prev) ----
      const unsigned short* hAp = t ? P.hA + (size_t)((t - 1) & 1) * SLOT : P.henc;
      stageA(32, nullptr, hAp, nullptr, 0);
      __syncthreads();
      f32x16 acc = runMfma(32, P.wpd0_h, P.wpd0_l);
      dump(acc);
      __syncthreads();
      if (ew){
        float din = 0.0f;
        if (t){
          unsigned pv = __hip_atomic_load((const unsigned*)&P.pred[(t - 1) * 256 + s_g],
                                          __ATOMIC_RELAXED, __HIP_MEMORY_SCOPE_SYSTEM);
          din = __builtin_bit_cast(float, pv);
        }
        unsigned short* oA = P.hA + (size_t)(t & 1) * SLOT;
        float h4[4];
        #pragma unroll
        for (int i = 0; i < 4; ++i){
          int c0 = u4 * 16 + 4 * i;
          float4 a = *(const float4*)&gdump[(0 * 32 + s_loc) * 68 + c0];
          float4 b = *(const float4*)&gdump[(1 * 32 + s_loc) * 68 + c0];
          float ii = sigm(a.x + b.x + cb0r[i][0] + din * w0r[i][0]);
          float f = sigm(a.y + b.y + cb0r[i][1] + din * w0r[i][1]);
          float g = tanh_f(a.z + b.z + cb0r[i][2] + din * w0r[i][2]);
          float o = sigm(a.w + b.w + cb0r[i][3] + din * w0r[i][3]);
          float c = f * cA[i] + ii * g;
          cA[i] = c;
          h4[i] = o * tanh_f(c);
        }
        write_h4(oA, h4);
      }
      gbar();

      // ---- cell 1 (K=512: hA current | hB prev) ----
      const unsigned short* hBp = t ? P.hB + (size_t)((t - 1) & 1) * SLOT : P.henc;
      stageA(64, nullptr, P.hA + (size_t)(t & 1) * SLOT, hBp, 32);
      __syncthreads();
      acc = runMfma(64, P.wpd1_h, P.wpd1_l);
      dump(acc);
      __syncthreads();
      if (ew){
        unsigned short* oB = P.hB + (size_t)(t & 1) * SLOT;
        float h4[4], part = 0.0f;
        #pragma unroll
        for (int i = 0; i < 4; ++i){
          int c0 = u4 * 16 + 4 * i;
          float4 a = *(const float4*)&gdump[(0 * 32 + s_loc) * 68 + c0];
          float4 b = *(const float4*)&gdump[(1 * 32 + s_loc) * 68 + c0];
          float ii = sigm(a.x + b.x + cb1r[i][0]);
          float f = sigm(a.y + b.y + cb1r[i][1]);
          float g = tanh_f(a.z + b.z + cb1r[i][2]);
          float o = sigm(a.w + b.w + cb1r[i][3]);
          float c = f * cB[i] + ii * g;
          cB[i] = c;
          float h = o * tanh_f(c);
          h4[i] = h;
          part += fcwr[i] * h;
        }
        write_h4(oB, h4);
        redl[u4 * 32 + s_loc] = part;
      }
      __syncthreads();
      if (tid < 32){
        float sum = redl[tid] + redl[32 + tid] + redl[64 + tid] + redl[96 + tid];
        float oldv = __hip_atomic_fetch_add(&P.pred[t * 256 + sgp * 32 + tid], sum,
                                            __ATOMIC_RELAXED, __HIP_MEMORY_SCOPE_SYSTEM);
        asm volatile("" :: "v"(oldv));   // force returning form (performed at MALL)
      }
      gbar();
    }
  }

  // ---------------- output ----------------
  if (cbk == 0){
    for (int i = tid; i < 32 * 24; i += 256){
      int sl = i / 24, tt = i % 24;
      unsigned pv = __hip_atomic_load((const unsigned*)&P.pred[tt * 256 + sgp * 32 + sl],
                                      __ATOMIC_RELAXED, __HIP_MEMORY_SCOPE_SYSTEM);
      P.out[(size_t)(sgp * 32 + sl) * 24 + tt] = __builtin_bit_cast(float, pv);
    }
  }
}

extern "C" void kernel_launch(void* const* d_in, const int* in_sizes, int n_in,
                              void* d_out, int out_size, void* d_ws, size_t ws_size,
                              hipStream_t stream){
  (void)in_sizes; (void)n_in; (void)out_size; (void)ws_size;
  Params P;
  P.x = (const float*)d_in[0];   P.s_in = (const float*)d_in[1];
  P.Wf = (const float*)d_in[2];  P.bf = (const float*)d_in[3];
  P.Wo = (const float*)d_in[4];  P.bo = (const float*)d_in[5];
  P.Wi = (const float*)d_in[6];  P.bi = (const float*)d_in[7];
  P.Wg = (const float*)d_in[8];  P.bg = (const float*)d_in[9];
  P.Wsi = (const float*)d_in[10]; P.bsi = (const float*)d_in[11];
  P.Wsg = (const float*)d_in[12]; P.bsg = (const float*)d_in[13];
  P.eWih = (const float*)d_in[14]; P.eWhh = (const float*)d_in[15];
  P.ebih = (const float*)d_in[16]; P.ebhh = (const float*)d_in[17];
  P.dWih0 = (const float*)d_in[18]; P.dWhh0 = (const float*)d_in[19];
  P.dbih0 = (const float*)d_in[20]; P.dbhh0 = (const float*)d_in[21];
  P.dWih1 = (const float*)d_in[22]; P.dWhh1 = (const float*)d_in[23];
  P.dbih1 = (const float*)d_in[24]; P.dbhh1 = (const float*)d_in[25];
  P.fcW = (const float*)d_in[26]; P.fcb = (const float*)d_in[27];
  P.out = (float*)d_out;

  char* base = (char*)d_ws;
  size_t off = 0;
  auto take = [&](size_t bytes) -> char* {
    char* r = base + off;
    off = (off + bytes + 255) & ~(size_t)255;
    return r;
  };
  P.ctrl    = (unsigned*)take(4096);
  P.wpea_h  = (unsigned short*)take((size_t)294912 * 2);
  P.wpea_l  = (unsigned short*)take((size_t)294912 * 2);
  P.wpenc_h = (unsigned short*)take((size_t)524288 * 2);
  P.wpenc_l = (unsigned short*)take((size_t)524288 * 2);
  P.wpd0_h  = (unsigned short*)take((size_t)262144 * 2);
  P.wpd0_l  = (unsigned short*)take((size_t)262144 * 2);
  P.wpd1_h  = (unsigned short*)take((size_t)524288 * 2);
  P.wpd1_l  = (unsigned short*)take((size_t)524288 * 2);
  P.xp      = (unsigned short*)take((size_t)XP_TOTAL * 2);
  P.si_v    = (float*)take((size_t)65536 * 4);
  P.sg_v    = (float*)take((size_t)65536 * 4);
  P.cbea    = (float*)take(4096);
  P.cbenc   = (float*)take(4096);
  P.cbd0    = (float*)take(4096);
  P.cbd1    = (float*)take(4096);
  P.w0v     = (float*)take(4096);
  P.fcw     = (float*)take(1024);
  P.pred    = (float*)take((size_t)6144 * 4);
  P.henc    = (unsigned short*)take((size_t)2 * 131072 * 2);
  P.hA      = (unsigned short*)take((size_t)2 * 131072 * 2);
  P.hB      = (unsigned short*)take((size_t)2 * 131072 * 2);
  P.hseq    = (unsigned short*)take((size_t)365 * 131072 * 2);

  hipMemsetAsync(d_ws, 0, 4096, stream);
  hipLaunchKernelGGL(ea_lstm_fused, dim3(128), dim3(256), 0, stream, P);
}

// Round 7
// 9735.454 us; speedup vs baseline: 1.0394x; 1.0394x over previous
//
#include <hip/hip_runtime.h>
#include <stdint.h>

typedef __bf16 bf16x8 __attribute__((ext_vector_type(8)));
typedef float f32x16 __attribute__((ext_vector_type(16)));

struct Params {
  const float *x, *s_in, *Wf, *bf, *Wo, *bo, *Wi, *bi, *Wg, *bg;
  const float *Wsi, *bsi, *Wsg, *bsg;
  const float *eWih, *eWhh, *ebih, *ebhh;
  const float *dWih0, *dWhh0, *dbih0, *dbhh0;
  const float *dWih1, *dWhh1, *dbih1, *dbhh1;
  const float *fcW, *fcb;
  float* out;
  unsigned* ctrl;
  unsigned short *wpea_h, *wpea_l, *wpenc_h, *wpenc_l;
  unsigned short *wpd0_h, *wpd0_l, *wpd1_h, *wpd1_l;
  unsigned short *xp_h, *xp_l;
  float *si_v, *sg_v, *cbea, *cbenc, *cbd0, *cbd1, *w0v, *fcw, *pred;
  unsigned short *henc, *hA, *hB, *hseq;
};

#define SLOT 131072   // elems per h slot: [plane2][kp32][s256][j8]

__device__ __forceinline__ unsigned short f2bf(float f){
  unsigned u = __builtin_bit_cast(unsigned, f);
  u += 0x7FFFu + ((u >> 16) & 1u);
  return (unsigned short)(u >> 16);
}
__device__ __forceinline__ float bf2f(unsigned short h){
  return __builtin_bit_cast(float, ((unsigned)h) << 16);
}
__device__ __forceinline__ float sigm(float v){ return 1.0f / (1.0f + __expf(-v)); }
__device__ __forceinline__ float tanh_f(float v){
  float a = fabsf(v);
  float e = __expf(-2.0f * a);
  float t = (1.0f - e) / (1.0f + e);
  return __builtin_copysignf(t, v);
}

extern "C" __global__ void __launch_bounds__(256, 1) ea_lstm_fused(Params P){
  __shared__ __align__(16) unsigned short aLds[32768];   // [plane2][kp(<=64)][s32][j8]
  __shared__ __align__(16) float gdump[32 * 132];        // [s32][col128 +4 pad]
  __shared__ __align__(16) float redl[32 * 33];

  const int tid = threadIdx.x;
  const int blk = blockIdx.x;
  const int sgp = blk & 7;    // sample group (dispatch round-robin -> XCD-affine heuristic)
  const int cbk = blk >> 3;   // column block 0..7 (128 gate cols each)
  const int lane = tid & 63;
  const int wv = tid >> 6;
  const int gtid = blk * 256 + tid;
  const int kgl = lane >> 5;
  const int aln = lane & 31;

  // ---------------- precompute (all 64 blocks) ----------------
  {
    for (int e = gtid; e < 294912; e += 16384){           // EA weights [288 x 1024]
      int j = e & 7, kg = (e >> 3) & 1, col = (e >> 4) & 1023, kt = e >> 14;
      int k = kt * 16 + kg * 8 + j;
      int u = col >> 2, g = col & 3;
      const float* Wp = (g == 0) ? P.Wf : (g == 1) ? P.Wo : (g == 2) ? P.Wi : P.Wg;
      float w = Wp[u * 288 + k];
      unsigned short hi = f2bf(w);
      P.wpea_h[e] = hi; P.wpea_l[e] = f2bf(w - bf2f(hi));
    }
    for (int e = gtid; e < 524288; e += 16384){           // enc [512 x 1024]
      int j = e & 7, kg = (e >> 3) & 1, col = (e >> 4) & 1023, kt = e >> 14;
      int k = kt * 16 + kg * 8 + j;
      int u = col >> 2, g = col & 3, row = g * 256 + u;
      float w = (k < 256) ? P.eWih[row * 256 + k] : P.eWhh[row * 256 + (k - 256)];
      unsigned short hi = f2bf(w);
      P.wpenc_h[e] = hi; P.wpenc_l[e] = f2bf(w - bf2f(hi));
    }
    for (int e = gtid; e < 262144; e += 16384){           // dec0 [256 x 1024]
      int j = e & 7, kg = (e >> 3) & 1, col = (e >> 4) & 1023, kt = e >> 14;
      int k = kt * 16 + kg * 8 + j;
      int u = col >> 2, g = col & 3, row = g * 256 + u;
      float w = P.dWhh0[row * 256 + k];
      unsigned short hi = f2bf(w);
      P.wpd0_h[e] = hi; P.wpd0_l[e] = f2bf(w - bf2f(hi));
    }
    for (int e = gtid; e < 524288; e += 16384){           // dec1 [512 x 1024]
      int j = e & 7, kg = (e >> 3) & 1, col = (e >> 4) & 1023, kt = e >> 14;
      int k = kt * 16 + kg * 8 + j;
      int u = col >> 2, g = col & 3, row = g * 256 + u;
      float w = (k < 256) ? P.dWih1[row * 256 + k] : P.dWhh1[row * 256 + (k - 256)];
      unsigned short hi = f2bf(w);
      P.wpd1_h[e] = hi; P.wpd1_l[e] = f2bf(w - bf2f(hi));
    }
    for (int e = gtid; e < 2990080; e += 16384){          // x -> [t][kp4][s256][j8]
      int j = e & 7, sl = (e >> 3) & 255, kp = (e >> 11) & 3, t = e >> 13;
      int f = kp * 8 + j;
      float w = P.x[((size_t)sl * 365 + t) * 32 + f];
      unsigned short hi = f2bf(w);
      P.xp_h[e] = hi; P.xp_l[e] = f2bf(w - bf2f(hi));
    }
    for (int e = gtid; e < 65536; e += 16384){            // si/sg statics (incl. bi/bg)
      int u = e & 255, b = e >> 8;
      float ai = P.bsi[u] + P.bi[u];
      float ag = P.bsg[u] + P.bg[u];
      for (int k = 0; k < 27; ++k){
        float sv = P.s_in[b * 27 + k];
        ai += sv * P.Wsi[u * 27 + k];
        ag += sv * P.Wsg[u * 27 + k];
      }
      P.si_v[b * 256 + u] = ai;
      P.sg_v[b * 256 + u] = ag;
    }
    for (int e = gtid; e < 1024; e += 16384){             // col biases / vectors
      int u = e >> 2, g = e & 3, row = g * 256 + u;
      P.cbea[e] = (g == 0) ? P.bf[u] : (g == 1) ? P.bo[u] : 0.0f;
      P.cbenc[e] = P.ebih[row] + P.ebhh[row];
      P.cbd0[e]  = P.dbih0[row] + P.dbhh0[row];
      P.cbd1[e]  = P.dbih1[row] + P.dbhh1[row];
      P.w0v[e]   = P.dWih0[row];
      if (e < 256) P.fcw[e] = P.fcW[e];
    }
    for (int e = gtid; e < 6144; e += 16384) P.pred[e] = P.fcb[0];
  }

  // global barrier (one time, 64 blocks)
  __syncthreads();
  if (tid == 0){
    unsigned n = __hip_atomic_fetch_add(P.ctrl, 1u, __ATOMIC_ACQ_REL, __HIP_MEMORY_SCOPE_AGENT) + 1u;
    if (n == 64u) __hip_atomic_store(P.ctrl + 16, 1u, __ATOMIC_RELEASE, __HIP_MEMORY_SCOPE_AGENT);
    else while (__hip_atomic_load(P.ctrl + 16, __ATOMIC_ACQUIRE, __HIP_MEMORY_SCOPE_AGENT) < 1u)
      __builtin_amdgcn_s_sleep(2);
  }
  __syncthreads();

  // ---------------- group barrier (round-1 proven: ACQ_REL agent) ----------------
  unsigned* gctr  = P.ctrl + 32 + 32 * sgp;
  unsigned* gflag = gctr + 16;
  unsigned gphase = 0;

  const int u_loc = tid & 31;
  const int u_g = cbk * 32 + u_loc;
  int s_loc[4], s_g[4];
  #pragma unroll
  for (int q = 0; q < 4; ++q){ s_loc[q] = 8 * q + (tid >> 5); s_g[q] = sgp * 32 + s_loc[q]; }

  auto gbar = [&](){
    ++gphase;
    __syncthreads();
    if (tid == 0){
      unsigned n = __hip_atomic_fetch_add(gctr, 1u, __ATOMIC_ACQ_REL, __HIP_MEMORY_SCOPE_AGENT) + 1u;
      if (n == 8u * gphase) __hip_atomic_store(gflag, gphase, __ATOMIC_RELEASE, __HIP_MEMORY_SCOPE_AGENT);
      else while (__hip_atomic_load(gflag, __ATOMIC_ACQUIRE, __HIP_MEMORY_SCOPE_AGENT) < gphase)
        __builtin_amdgcn_s_sleep(2);
    }
    __syncthreads();
  };

  // ---------------- single-shot A-tile staging ----------------
  // aLds layout: [plane][p(kpT)][s32][j8]; x occupies p<4 when xh!=null
  auto stage = [&](int kpT, const unsigned short* xh, const unsigned short* xl,
                   const unsigned short* sA, const unsigned short* sB, int kpB0){
    #pragma unroll 1
    for (int plane = 0; plane < 2; ++plane){
      const unsigned short* xp = plane ? xl : xh;
      for (int idx = tid; idx < kpT * 32; idx += 256){
        int p = idx >> 5, sl = idx & 31;
        uint4 v = make_uint4(0u, 0u, 0u, 0u);
        if (xh && p < 4){
          v = *(const uint4*)(xp + ((size_t)p * 256 + sgp * 32 + sl) * 8);
        } else {
          int hk = p - (xh ? 4 : 0);
          const unsigned short* sptr = sA;
          if (sB && hk >= kpB0){ sptr = sB; hk -= kpB0; }
          if (sptr) v = *(const uint4*)(sptr + (size_t)plane * 65536 + ((size_t)hk * 256 + sgp * 32 + sl) * 8);
        }
        *(uint4*)&aLds[((plane * kpT + p) * 32 + sl) * 8] = v;
      }
    }
  };

  // ---------------- MFMA: 4 waves = 4 col-tiles of 32, full K each ----------------
  auto runMfma = [&](int kpT, const unsigned short* wh, const unsigned short* wl) -> f32x16 {
    f32x16 acc;
    #pragma unroll
    for (int r = 0; r < 16; ++r) acc[r] = 0.0f;
    const int nkt = kpT >> 1;
    const int colg = cbk * 128 + wv * 32 + aln;
    #pragma unroll 4
    for (int kt = 0; kt < nkt; ++kt){
      int p = 2 * kt + kgl;
      bf16x8 ahi = __builtin_bit_cast(bf16x8, *(const uint4*)&aLds[((0 * kpT + p) * 32 + aln) * 8]);
      bf16x8 alo = __builtin_bit_cast(bf16x8, *(const uint4*)&aLds[((1 * kpT + p) * 32 + aln) * 8]);
      size_t be = ((size_t)kt * 1024 + colg) * 16 + (size_t)kgl * 8;
      bf16x8 bhi = __builtin_bit_cast(bf16x8, *(const uint4*)(wh + be));
      bf16x8 blo = __builtin_bit_cast(bf16x8, *(const uint4*)(wl + be));
      acc = __builtin_amdgcn_mfma_f32_32x32x16_bf16(alo, bhi, acc, 0, 0, 0);
      acc = __builtin_amdgcn_mfma_f32_32x32x16_bf16(ahi, blo, acc, 0, 0, 0);
      acc = __builtin_amdgcn_mfma_f32_32x32x16_bf16(ahi, bhi, acc, 0, 0, 0);
    }
    return acc;
  };

  auto dump = [&](const f32x16& acc){
    #pragma unroll
    for (int r = 0; r < 16; ++r){
      int row = (r & 3) + 8 * (r >> 2) + 4 * kgl;    // verified C/D layout
      gdump[row * 132 + wv * 32 + aln] = acc[r];
    }
  };

  auto write_h = [&](unsigned short* slot, int q, float h){
    int kp = u_g >> 3, j = u_g & 7;
    size_t o = ((size_t)kp * 256 + s_g[q]) * 8 + j;
    unsigned short hi = f2bf(h);
    slot[o] = hi;
    slot[65536 + o] = f2bf(h - bf2f(hi));
  };

  float cbr[4];
  float cst[4] = {0.f, 0.f, 0.f, 0.f};

  // ---------------- EA phase ----------------
  {
    float sir[4], sgr[4];
    #pragma unroll
    for (int g = 0; g < 4; ++g) cbr[g] = P.cbea[4 * u_g + g];
    #pragma unroll
    for (int q = 0; q < 4; ++q){
      sir[q] = P.si_v[s_g[q] * 256 + u_g];
      sgr[q] = P.sg_v[s_g[q] * 256 + u_g];
    }
    for (int t = 0; t < 365; ++t){
      const unsigned short* hslot = t ? P.hseq + (size_t)(t - 1) * SLOT : nullptr;
      stage(36, P.xp_h + (size_t)t * 8192, P.xp_l + (size_t)t * 8192, hslot, nullptr, 0);
      __syncthreads();
      f32x16 acc = runMfma(36, P.wpea_h, P.wpea_l);
      dump(acc);
      __syncthreads();
      unsigned short* oslot = P.hseq + (size_t)t * SLOT;
      #pragma unroll
      for (int q = 0; q < 4; ++q){
        float4 g4 = *(const float4*)&gdump[s_loc[q] * 132 + 4 * u_loc];
        float f = sigm(g4.x + cbr[0]);
        float o = sigm(g4.y + cbr[1]);
        float i = sigm(g4.z + sir[q]);
        float g = tanh_f(g4.w + sgr[q]);
        float c = f * cst[q] + i * g;
        cst[q] = c;
        write_h(oslot, q, o * tanh_f(c));
      }
      gbar();
    }
  }

  // ---------------- encoder phase ----------------
  {
    #pragma unroll
    for (int g = 0; g < 4; ++g) cbr[g] = P.cbenc[4 * u_g + g];
    for (int t = 0; t < 365; ++t){
      const unsigned short* hprev = t ? P.henc + (size_t)((t - 1) & 1) * SLOT
                                      : P.hseq + (size_t)364 * SLOT;
      stage(64, nullptr, nullptr, P.hseq + (size_t)t * SLOT, hprev, 32);
      __syncthreads();
      f32x16 acc = runMfma(64, P.wpenc_h, P.wpenc_l);
      dump(acc);
      __syncthreads();
      unsigned short* oslot = P.henc + (size_t)(t & 1) * SLOT;
      #pragma unroll
      for (int q = 0; q < 4; ++q){
        float4 g4 = *(const float4*)&gdump[s_loc[q] * 132 + 4 * u_loc];
        float i = sigm(g4.x + cbr[0]);
        float f = sigm(g4.y + cbr[1]);
        float g = tanh_f(g4.z + cbr[2]);
        float o = sigm(g4.w + cbr[3]);
        float c = f * cst[q] + i * g;
        cst[q] = c;
        write_h(oslot, q, o * tanh_f(c));
      }
      gbar();
    }
  }

  // ---------------- decoder phase ----------------
  {
    float cb0r[4], cb1r[4], w0r[4];
    #pragma unroll
    for (int g = 0; g < 4; ++g){
      cb0r[g] = P.cbd0[4 * u_g + g];
      cb1r[g] = P.cbd1[4 * u_g + g];
      w0r[g]  = P.w0v[4 * u_g + g];
    }
    float fcwr = P.fcw[u_g];
    float cA[4], cB[4];
    #pragma unroll
    for (int q = 0; q < 4; ++q){ cA[q] = cst[q]; cB[q] = cst[q]; }

    for (int t = 0; t < 24; ++t){
      // ---- cell 0 (K=256: hA prev) ----
      const unsigned short* hAp = t ? P.hA + (size_t)((t - 1) & 1) * SLOT : P.henc;
      stage(32, nullptr, nullptr, hAp, nullptr, 0);
      __syncthreads();
      f32x16 acc = runMfma(32, P.wpd0_h, P.wpd0_l);
      dump(acc);
      __syncthreads();
      unsigned short* oA = P.hA + (size_t)(t & 1) * SLOT;
      #pragma unroll
      for (int q = 0; q < 4; ++q){
        float din = t ? P.pred[(t - 1) * 256 + s_g[q]] : 0.0f;
        float4 g4 = *(const float4*)&gdump[s_loc[q] * 132 + 4 * u_loc];
        float i = sigm(g4.x + cb0r[0] + din * w0r[0]);
        float f = sigm(g4.y + cb0r[1] + din * w0r[1]);
        float g = tanh_f(g4.z + cb0r[2] + din * w0r[2]);
        float o = sigm(g4.w + cb0r[3] + din * w0r[3]);
        float c = f * cA[q] + i * g;
        cA[q] = c;
        write_h(oA, q, o * tanh_f(c));
      }
      gbar();

      // ---- cell 1 (K=512: hA current | hB prev) ----
      const unsigned short* hBp = t ? P.hB + (size_t)((t - 1) & 1) * SLOT : P.henc;
      stage(64, nullptr, nullptr, P.hA + (size_t)(t & 1) * SLOT, hBp, 32);
      __syncthreads();
      acc = runMfma(64, P.wpd1_h, P.wpd1_l);
      dump(acc);
      __syncthreads();
      unsigned short* oB = P.hB + (size_t)(t & 1) * SLOT;
      #pragma unroll
      for (int q = 0; q < 4; ++q){
        float4 g4 = *(const float4*)&gdump[s_loc[q] * 132 + 4 * u_loc];
        float i = sigm(g4.x + cb1r[0]);
        float f = sigm(g4.y + cb1r[1]);
        float g = tanh_f(g4.z + cb1r[2]);
        float o = sigm(g4.w + cb1r[3]);
        float c = f * cB[q] + i * g;
        cB[q] = c;
        float h = o * tanh_f(c);
        write_h(oB, q, h);
        redl[u_loc * 33 + s_loc[q]] = fcwr * h;
      }
      __syncthreads();
      if (tid < 32){
        float sum = 0.0f;
        #pragma unroll
        for (int u = 0; u < 32; ++u) sum += redl[u * 33 + tid];
        atomicAdd(&P.pred[t * 256 + sgp * 32 + tid], sum);
      }
      gbar();
    }
  }

  // ---------------- output ----------------
  if (cbk == 0){
    for (int i = tid; i < 32 * 24; i += 256){
      int sl = i / 24, tt = i % 24;
      P.out[(size_t)(sgp * 32 + sl) * 24 + tt] = P.pred[tt * 256 + sgp * 32 + sl];
    }
  }
}

extern "C" void kernel_launch(void* const* d_in, const int* in_sizes, int n_in,
                              void* d_out, int out_size, void* d_ws, size_t ws_size,
                              hipStream_t stream){
  (void)in_sizes; (void)n_in; (void)out_size; (void)ws_size;
  Params P;
  P.x = (const float*)d_in[0];   P.s_in = (const float*)d_in[1];
  P.Wf = (const float*)d_in[2];  P.bf = (const float*)d_in[3];
  P.Wo = (const float*)d_in[4];  P.bo = (const float*)d_in[5];
  P.Wi = (const float*)d_in[6];  P.bi = (const float*)d_in[7];
  P.Wg = (const float*)d_in[8];  P.bg = (const float*)d_in[9];
  P.Wsi = (const float*)d_in[10]; P.bsi = (const float*)d_in[11];
  P.Wsg = (const float*)d_in[12]; P.bsg = (const float*)d_in[13];
  P.eWih = (const float*)d_in[14]; P.eWhh = (const float*)d_in[15];
  P.ebih = (const float*)d_in[16]; P.ebhh = (const float*)d_in[17];
  P.dWih0 = (const float*)d_in[18]; P.dWhh0 = (const float*)d_in[19];
  P.dbih0 = (const float*)d_in[20]; P.dbhh0 = (const float*)d_in[21];
  P.dWih1 = (const float*)d_in[22]; P.dWhh1 = (const float*)d_in[23];
  P.dbih1 = (const float*)d_in[24]; P.dbhh1 = (const float*)d_in[25];
  P.fcW = (const float*)d_in[26]; P.fcb = (const float*)d_in[27];
  P.out = (float*)d_out;

  char* base = (char*)d_ws;
  size_t off = 0;
  auto take = [&](size_t bytes) -> char* {
    char* r = base + off;
    off = (off + bytes + 255) & ~(size_t)255;
    return r;
  };
  P.ctrl    = (unsigned*)take(4096);
  P.wpea_h  = (unsigned short*)take((size_t)294912 * 2);
  P.wpea_l  = (unsigned short*)take((size_t)294912 * 2);
  P.wpenc_h = (unsigned short*)take((size_t)524288 * 2);
  P.wpenc_l = (unsigned short*)take((size_t)524288 * 2);
  P.wpd0_h  = (unsigned short*)take((size_t)262144 * 2);
  P.wpd0_l  = (unsigned short*)take((size_t)262144 * 2);
  P.wpd1_h  = (unsigned short*)take((size_t)524288 * 2);
  P.wpd1_l  = (unsigned short*)take((size_t)524288 * 2);
  P.xp_h    = (unsigned short*)take((size_t)2990080 * 2);
  P.xp_l    = (unsigned short*)take((size_t)2990080 * 2);
  P.si_v    = (float*)take((size_t)65536 * 4);
  P.sg_v    = (float*)take((size_t)65536 * 4);
  P.cbea    = (float*)take(4096);
  P.cbenc   = (float*)take(4096);
  P.cbd0    = (float*)take(4096);
  P.cbd1    = (float*)take(4096);
  P.w0v     = (float*)take(4096);
  P.fcw     = (float*)take(1024);
  P.pred    = (float*)take((size_t)6144 * 4);
  P.henc    = (unsigned short*)take((size_t)2 * 131072 * 2);
  P.hA      = (unsigned short*)take((size_t)2 * 131072 * 2);
  P.hB      = (unsigned short*)take((size_t)2 * 131072 * 2);
  P.hseq    = (unsigned short*)take((size_t)365 * 131072 * 2);

  hipMemsetAsync(d_ws, 0, 4096, stream);
  hipLaunchKernelGGL(ea_lstm_fused, dim3(64), dim3(256), 0, stream, P);
}

// Round 8
// 9696.513 us; speedup vs baseline: 1.0436x; 1.0040x over previous
//
#include <hip/hip_runtime.h>
#include <stdint.h>

typedef __bf16 bf16x8 __attribute__((ext_vector_type(8)));
typedef float f32x16 __attribute__((ext_vector_type(16)));
typedef unsigned long long u64;

struct Params {
  const float *x, *s_in, *Wf, *bf, *Wo, *bo, *Wi, *bi, *Wg, *bg;
  const float *Wsi, *bsi, *Wsg, *bsg;
  const float *eWih, *eWhh, *ebih, *ebhh;
  const float *dWih0, *dWhh0, *dbih0, *dbhh0;
  const float *dWih1, *dWhh1, *dbih1, *dbhh1;
  const float *fcW, *fcb;
  float* out;
  unsigned* ctrl;
  unsigned short *wpea_h, *wpea_l, *wpenc_h, *wpenc_l;
  unsigned short *wpd0_h, *wpd0_l, *wpd1_h, *wpd1_l;
  unsigned short *xp_h, *xp_l;
  float *si_v, *sg_v, *cbea, *cbenc, *cbd0, *cbd1, *w0v, *fcw, *pred;
  unsigned short *henc, *hA, *hB, *hseq;
};

#define SLOT 131072   // elems per h slot: [plane2][s256][u256]

__device__ __forceinline__ unsigned short f2bf(float f){
  unsigned u = __builtin_bit_cast(unsigned, f);
  u += 0x7FFFu + ((u >> 16) & 1u);
  return (unsigned short)(u >> 16);
}
__device__ __forceinline__ float bf2f(unsigned short h){
  return __builtin_bit_cast(float, ((unsigned)h) << 16);
}
__device__ __forceinline__ float sigm(float v){ return 1.0f / (1.0f + __expf(-v)); }
__device__ __forceinline__ float tanh_f(float v){
  float a = fabsf(v);
  float e = __expf(-2.0f * a);
  float t = (1.0f - e) / (1.0f + e);
  return __builtin_copysignf(t, v);
}

// relaxed AGENT-scope atomics: device-coherent at the MALL, NO wbl2/inv emitted
__device__ __forceinline__ u64 ag_ld64(const unsigned short* p){
  return __hip_atomic_load((const u64*)p, __ATOMIC_RELAXED, __HIP_MEMORY_SCOPE_AGENT);
}
__device__ __forceinline__ unsigned ag_ld32(const float* p){
  return __hip_atomic_load((const unsigned*)p, __ATOMIC_RELAXED, __HIP_MEMORY_SCOPE_AGENT);
}
// publish via RETURNING swap: performed at the MALL before vmcnt-ack
__device__ __forceinline__ void ag_swap64(unsigned short* p, u64 v){
  u64 old = __hip_atomic_exchange((u64*)p, v, __ATOMIC_RELAXED, __HIP_MEMORY_SCOPE_AGENT);
  asm volatile("" :: "v"(old));
}

extern "C" __global__ void __launch_bounds__(256, 1) ea_lstm_fused(Params P){
  __shared__ __align__(16) unsigned short aLds[32768];   // [plane2][kp(<=64)][s32][j8]
  __shared__ __align__(16) float gdump[32 * 132];        // [s32][col128 +4 pad]
  __shared__ __align__(16) float redl[256];              // [u8][s32]

  const int tid = threadIdx.x;
  const int blk = blockIdx.x;
  const int sgp = blk & 7;    // sample group (round-robin dispatch -> XCD-affinity heuristic)
  const int cbk = blk >> 3;   // column block 0..7 (128 gate cols = 32 units)
  const int lane = tid & 63;
  const int wv = tid >> 6;
  const int gtid = blk * 256 + tid;
  const int kgl = lane >> 5;
  const int aln = lane & 31;

  // ---------------- precompute (all 64 blocks) ----------------
  {
    for (int e = gtid; e < 294912; e += 16384){           // EA weights [288 x 1024]
      int j = e & 7, kg = (e >> 3) & 1, col = (e >> 4) & 1023, kt = e >> 14;
      int k = kt * 16 + kg * 8 + j;
      int u = col >> 2, g = col & 3;
      const float* Wp = (g == 0) ? P.Wf : (g == 1) ? P.Wo : (g == 2) ? P.Wi : P.Wg;
      float w = Wp[u * 288 + k];
      unsigned short hi = f2bf(w);
      P.wpea_h[e] = hi; P.wpea_l[e] = f2bf(w - bf2f(hi));
    }
    for (int e = gtid; e < 524288; e += 16384){           // enc [512 x 1024]
      int j = e & 7, kg = (e >> 3) & 1, col = (e >> 4) & 1023, kt = e >> 14;
      int k = kt * 16 + kg * 8 + j;
      int u = col >> 2, g = col & 3, row = g * 256 + u;
      float w = (k < 256) ? P.eWih[row * 256 + k] : P.eWhh[row * 256 + (k - 256)];
      unsigned short hi = f2bf(w);
      P.wpenc_h[e] = hi; P.wpenc_l[e] = f2bf(w - bf2f(hi));
    }
    for (int e = gtid; e < 262144; e += 16384){           // dec0 [256 x 1024]
      int j = e & 7, kg = (e >> 3) & 1, col = (e >> 4) & 1023, kt = e >> 14;
      int k = kt * 16 + kg * 8 + j;
      int u = col >> 2, g = col & 3, row = g * 256 + u;
      float w = P.dWhh0[row * 256 + k];
      unsigned short hi = f2bf(w);
      P.wpd0_h[e] = hi; P.wpd0_l[e] = f2bf(w - bf2f(hi));
    }
    for (int e = gtid; e < 524288; e += 16384){           // dec1 [512 x 1024]
      int j = e & 7, kg = (e >> 3) & 1, col = (e >> 4) & 1023, kt = e >> 14;
      int k = kt * 16 + kg * 8 + j;
      int u = col >> 2, g = col & 3, row = g * 256 + u;
      float w = (k < 256) ? P.dWih1[row * 256 + k] : P.dWhh1[row * 256 + (k - 256)];
      unsigned short hi = f2bf(w);
      P.wpd1_h[e] = hi; P.wpd1_l[e] = f2bf(w - bf2f(hi));
    }
    for (int e = gtid; e < 2990080; e += 16384){          // x -> [t][kp4][s256][j8]
      int j = e & 7, sl = (e >> 3) & 255, kp = (e >> 11) & 3, t = e >> 13;
      int f = kp * 8 + j;
      float w = P.x[((size_t)sl * 365 + t) * 32 + f];
      unsigned short hi = f2bf(w);
      P.xp_h[e] = hi; P.xp_l[e] = f2bf(w - bf2f(hi));
    }
    for (int e = gtid; e < 65536; e += 16384){            // si/sg statics (incl. bi/bg)
      int u = e & 255, b = e >> 8;
      float ai = P.bsi[u] + P.bi[u];
      float ag = P.bsg[u] + P.bg[u];
      for (int k = 0; k < 27; ++k){
        float sv = P.s_in[b * 27 + k];
        ai += sv * P.Wsi[u * 27 + k];
        ag += sv * P.Wsg[u * 27 + k];
      }
      P.si_v[b * 256 + u] = ai;
      P.sg_v[b * 256 + u] = ag;
    }
    for (int e = gtid; e < 1024; e += 16384){             // col biases / vectors
      int u = e >> 2, g = e & 3, row = g * 256 + u;
      P.cbea[e] = (g == 0) ? P.bf[u] : (g == 1) ? P.bo[u] : 0.0f;
      P.cbenc[e] = P.ebih[row] + P.ebhh[row];
      P.cbd0[e]  = P.dbih0[row] + P.dbhh0[row];
      P.cbd1[e]  = P.dbih1[row] + P.dbhh1[row];
      P.w0v[e]   = P.dWih0[row];
      if (e < 256) P.fcw[e] = P.fcW[e];
    }
    for (int e = gtid; e < 6144; e += 16384) P.pred[e] = P.fcb[0];
  }

  // one-time fenced barrier (ACQ_REL agent: wbl2 flushes precompute to MALL/HBM)
  __syncthreads();
  if (tid == 0){
    unsigned n = __hip_atomic_fetch_add(P.ctrl, 1u, __ATOMIC_ACQ_REL, __HIP_MEMORY_SCOPE_AGENT) + 1u;
    if (n == 64u) __hip_atomic_store(P.ctrl + 16, 1u, __ATOMIC_RELEASE, __HIP_MEMORY_SCOPE_AGENT);
    else while (__hip_atomic_load(P.ctrl + 16, __ATOMIC_ACQUIRE, __HIP_MEMORY_SCOPE_AGENT) < 1u)
      __builtin_amdgcn_s_sleep(2);
  }
  __syncthreads();

  // ---------------- group barrier: flat 8 flags, relaxed agent, no fences ----------------
  unsigned* gfl = P.ctrl + 64 + sgp * 8;
  unsigned gphase = 0;

  auto gbar = [&](){
    ++gphase;
    __syncthreads();   // per-wave vmcnt(0): all returning swaps performed at MALL
    if (tid == 0)
      __hip_atomic_store(&gfl[cbk], gphase, __ATOMIC_RELAXED, __HIP_MEMORY_SCOPE_AGENT);
    if (tid < 64){
      const unsigned* f = gfl + (tid & 7);
      for (;;){
        unsigned v = __hip_atomic_load(f, __ATOMIC_RELAXED, __HIP_MEMORY_SCOPE_AGENT);
        if (__all((int)(v >= gphase))) break;
        __builtin_amdgcn_s_sleep(1);
      }
    }
    __builtin_amdgcn_fence(__ATOMIC_ACQUIRE, "workgroup");   // compiler/LDS ordering only
    __syncthreads();
  };

  // ---------------- single-shot A-tile staging ----------------
  // aLds: [plane][p(kpT)][s32][j8]; x occupies p<4 when xh!=null; h via agent atomics
  auto stage = [&](int kpT, const unsigned short* xh, const unsigned short* xl,
                   const unsigned short* sA, const unsigned short* sB, int kpB0){
    for (int idx = tid; idx < kpT * 32; idx += 256){
      int p = idx >> 5, sl = idx & 31;
      #pragma unroll
      for (int plane = 0; plane < 2; ++plane){
        unsigned short* dst = &aLds[((plane * kpT + p) * 32 + sl) * 8];
        if (xh && p < 4){
          const unsigned short* xp = plane ? xl : xh;
          *(uint4*)dst = *(const uint4*)(xp + ((size_t)p * 256 + sgp * 32 + sl) * 8);
        } else {
          int hk = p - (xh ? 4 : 0);
          const unsigned short* sptr = sA;
          if (sB && hk >= kpB0){ sptr = sB; hk -= kpB0; }
          if (sptr){
            const unsigned short* src = sptr + (size_t)plane * 65536
                                      + ((size_t)(sgp * 32 + sl) * 256 + hk * 8);
            ((u64*)dst)[0] = ag_ld64(src);
            ((u64*)dst)[1] = ag_ld64(src + 4);
          } else {
            ((u64*)dst)[0] = 0; ((u64*)dst)[1] = 0;
          }
        }
      }
    }
  };

  // ---------------- MFMA: 4 waves = 4 col-tiles of 32, full K each ----------------
  auto runMfma = [&](int kpT, const unsigned short* wh, const unsigned short* wl) -> f32x16 {
    f32x16 acc;
    #pragma unroll
    for (int r = 0; r < 16; ++r) acc[r] = 0.0f;
    const int nkt = kpT >> 1;
    const int colg = cbk * 128 + wv * 32 + aln;
    #pragma unroll 4
    for (int kt = 0; kt < nkt; ++kt){
      int p = 2 * kt + kgl;
      bf16x8 ahi = __builtin_bit_cast(bf16x8, *(const uint4*)&aLds[((0 * kpT + p) * 32 + aln) * 8]);
      bf16x8 alo = __builtin_bit_cast(bf16x8, *(const uint4*)&aLds[((1 * kpT + p) * 32 + aln) * 8]);
      size_t be = ((size_t)kt * 1024 + colg) * 16 + (size_t)kgl * 8;
      bf16x8 bhi = __builtin_bit_cast(bf16x8, *(const uint4*)(wh + be));
      bf16x8 blo = __builtin_bit_cast(bf16x8, *(const uint4*)(wl + be));
      acc = __builtin_amdgcn_mfma_f32_32x32x16_bf16(alo, bhi, acc, 0, 0, 0);
      acc = __builtin_amdgcn_mfma_f32_32x32x16_bf16(ahi, blo, acc, 0, 0, 0);
      acc = __builtin_amdgcn_mfma_f32_32x32x16_bf16(ahi, bhi, acc, 0, 0, 0);
    }
    return acc;
  };

  auto dump = [&](const f32x16& acc){
    #pragma unroll
    for (int r = 0; r < 16; ++r){
      int row = (r & 3) + 8 * (r >> 2) + 4 * kgl;    // verified C/D layout
      gdump[row * 132 + wv * 32 + aln] = acc[r];
    }
  };

  // elementwise: all 256 threads; thread = (sample s_loc, unit-quad u8)
  const int s_loc = tid & 31;
  const int u8 = tid >> 5;
  const int s_g = sgp * 32 + s_loc;
  const int u_g0 = cbk * 32 + u8 * 4;

  auto write_h4 = [&](unsigned short* slot, const float* h){
    u64 hi = 0, lo = 0;
    #pragma unroll
    for (int i = 0; i < 4; ++i){
      unsigned short hb = f2bf(h[i]);
      hi |= (u64)hb << (16 * i);
      lo |= (u64)f2bf(h[i] - bf2f(hb)) << (16 * i);
    }
    size_t o = (size_t)s_g * 256 + u_g0;
    ag_swap64(slot + o, hi);
    ag_swap64(slot + 65536 + o, lo);
  };

  float cst[4] = {0.f, 0.f, 0.f, 0.f};

  // ---------------- EA phase ----------------
  {
    float cbr[4][4], sir[4], sgr[4];
    #pragma unroll
    for (int i = 0; i < 4; ++i){
      float4 cb = *(const float4*)&P.cbea[4 * (u_g0 + i)];
      cbr[i][0] = cb.x; cbr[i][1] = cb.y; cbr[i][2] = cb.z; cbr[i][3] = cb.w;
      sir[i] = P.si_v[s_g * 256 + u_g0 + i];
      sgr[i] = P.sg_v[s_g * 256 + u_g0 + i];
    }
    for (int t = 0; t < 365; ++t){
      const unsigned short* hslot = t ? P.hseq + (size_t)(t - 1) * SLOT : nullptr;
      stage(36, P.xp_h + (size_t)t * 8192, P.xp_l + (size_t)t * 8192, hslot, nullptr, 0);
      __syncthreads();
      f32x16 acc = runMfma(36, P.wpea_h, P.wpea_l);
      dump(acc);
      __syncthreads();
      unsigned short* oslot = P.hseq + (size_t)t * SLOT;
      float h4[4];
      #pragma unroll
      for (int i = 0; i < 4; ++i){
        int c0 = 4 * (u8 * 4 + i);
        float4 g4 = *(const float4*)&gdump[s_loc * 132 + c0];
        float f = sigm(g4.x + cbr[i][0]);
        float o = sigm(g4.y + cbr[i][1]);
        float ii = sigm(g4.z + sir[i]);
        float g = tanh_f(g4.w + sgr[i]);
        float c = f * cst[i] + ii * g;
        cst[i] = c;
        h4[i] = o * tanh_f(c);
      }
      write_h4(oslot, h4);
      gbar();
    }
  }

  // ---------------- encoder phase ----------------
  {
    float cbr[4][4];
    #pragma unroll
    for (int i = 0; i < 4; ++i){
      float4 cb = *(const float4*)&P.cbenc[4 * (u_g0 + i)];
      cbr[i][0] = cb.x; cbr[i][1] = cb.y; cbr[i][2] = cb.z; cbr[i][3] = cb.w;
    }
    for (int t = 0; t < 365; ++t){
      const unsigned short* hprev = t ? P.henc + (size_t)((t - 1) & 1) * SLOT
                                      : P.hseq + (size_t)364 * SLOT;
      stage(64, nullptr, nullptr, P.hseq + (size_t)t * SLOT, hprev, 32);
      __syncthreads();
      f32x16 acc = runMfma(64, P.wpenc_h, P.wpenc_l);
      dump(acc);
      __syncthreads();
      unsigned short* oslot = P.henc + (size_t)(t & 1) * SLOT;
      float h4[4];
      #pragma unroll
      for (int i = 0; i < 4; ++i){
        int c0 = 4 * (u8 * 4 + i);
        float4 g4 = *(const float4*)&gdump[s_loc * 132 + c0];
        float ii = sigm(g4.x + cbr[i][0]);
        float f = sigm(g4.y + cbr[i][1]);
        float g = tanh_f(g4.z + cbr[i][2]);
        float o = sigm(g4.w + cbr[i][3]);
        float c = f * cst[i] + ii * g;
        cst[i] = c;
        h4[i] = o * tanh_f(c);
      }
      write_h4(oslot, h4);
      gbar();
    }
  }

  // ---------------- decoder phase ----------------
  {
    float cb0r[4][4], cb1r[4][4], w0r[4][4], fcwr[4];
    #pragma unroll
    for (int i = 0; i < 4; ++i){
      float4 c0v = *(const float4*)&P.cbd0[4 * (u_g0 + i)];
      float4 c1v = *(const float4*)&P.cbd1[4 * (u_g0 + i)];
      float4 wv4 = *(const float4*)&P.w0v[4 * (u_g0 + i)];
      cb0r[i][0] = c0v.x; cb0r[i][1] = c0v.y; cb0r[i][2] = c0v.z; cb0r[i][3] = c0v.w;
      cb1r[i][0] = c1v.x; cb1r[i][1] = c1v.y; cb1r[i][2] = c1v.z; cb1r[i][3] = c1v.w;
      w0r[i][0] = wv4.x; w0r[i][1] = wv4.y; w0r[i][2] = wv4.z; w0r[i][3] = wv4.w;
      fcwr[i] = P.fcw[u_g0 + i];
    }
    float cA[4], cB[4];
    #pragma unroll
    for (int i = 0; i < 4; ++i){ cA[i] = cst[i]; cB[i] = cst[i]; }

    for (int t = 0; t < 24; ++t){
      // ---- cell 0 (K=256: hA prev) ----
      const unsigned short* hAp = t ? P.hA + (size_t)((t - 1) & 1) * SLOT : P.henc;
      stage(32, nullptr, nullptr, hAp, nullptr, 0);
      __syncthreads();
      f32x16 acc = runMfma(32, P.wpd0_h, P.wpd0_l);
      dump(acc);
      __syncthreads();
      {
        float din = 0.0f;
        if (t) din = __builtin_bit_cast(float, ag_ld32(&P.pred[(t - 1) * 256 + s_g]));
        unsigned short* oA = P.hA + (size_t)(t & 1) * SLOT;
        float h4[4];
        #pragma unroll
        for (int i = 0; i < 4; ++i){
          int c0 = 4 * (u8 * 4 + i);
          float4 g4 = *(const float4*)&gdump[s_loc * 132 + c0];
          float ii = sigm(g4.x + cb0r[i][0] + din * w0r[i][0]);
          float f = sigm(g4.y + cb0r[i][1] + din * w0r[i][1]);
          float g = tanh_f(g4.z + cb0r[i][2] + din * w0r[i][2]);
          float o = sigm(g4.w + cb0r[i][3] + din * w0r[i][3]);
          float c = f * cA[i] + ii * g;
          cA[i] = c;
          h4[i] = o * tanh_f(c);
        }
        write_h4(oA, h4);
      }
      gbar();

      // ---- cell 1 (K=512: hA current | hB prev) ----
      const unsigned short* hBp = t ? P.hB + (size_t)((t - 1) & 1) * SLOT : P.henc;
      stage(64, nullptr, nullptr, P.hA + (size_t)(t & 1) * SLOT, hBp, 32);
      __syncthreads();
      acc = runMfma(64, P.wpd1_h, P.wpd1_l);
      dump(acc);
      __syncthreads();
      {
        unsigned short* oB = P.hB + (size_t)(t & 1) * SLOT;
        float h4[4], part = 0.0f;
        #pragma unroll
        for (int i = 0; i < 4; ++i){
          int c0 = 4 * (u8 * 4 + i);
          float4 g4 = *(const float4*)&gdump[s_loc * 132 + c0];
          float ii = sigm(g4.x + cb1r[i][0]);
          float f = sigm(g4.y + cb1r[i][1]);
          float g = tanh_f(g4.z + cb1r[i][2]);
          float o = sigm(g4.w + cb1r[i][3]);
          float c = f * cB[i] + ii * g;
          cB[i] = c;
          float h = o * tanh_f(c);
          h4[i] = h;
          part += fcwr[i] * h;
        }
        write_h4(oB, h4);
        redl[u8 * 32 + s_loc] = part;
      }
      __syncthreads();
      if (tid < 32){
        float sum = 0.0f;
        #pragma unroll
        for (int k = 0; k < 8; ++k) sum += redl[k * 32 + tid];
        float oldv = __hip_atomic_fetch_add(&P.pred[t * 256 + sgp * 32 + tid], sum,
                                            __ATOMIC_RELAXED, __HIP_MEMORY_SCOPE_AGENT);
        asm volatile("" :: "v"(oldv));   // returning form: performed at MALL
      }
      gbar();
    }
  }

  // ---------------- output ----------------
  if (cbk == 0){
    for (int i = tid; i < 32 * 24; i += 256){
      int sl = i / 24, tt = i % 24;
      unsigned pv = ag_ld32(&P.pred[tt * 256 + sgp * 32 + sl]);
      P.out[(size_t)(sgp * 32 + sl) * 24 + tt] = __builtin_bit_cast(float, pv);
    }
  }
}

extern "C" void kernel_launch(void* const* d_in, const int* in_sizes, int n_in,
                              void* d_out, int out_size, void* d_ws, size_t ws_size,
                              hipStream_t stream){
  (void)in_sizes; (void)n_in; (void)out_size; (void)ws_size;
  Params P;
  P.x = (const float*)d_in[0];   P.s_in = (const float*)d_in[1];
  P.Wf = (const float*)d_in[2];  P.bf = (const float*)d_in[3];
  P.Wo = (const float*)d_in[4];  P.bo = (const float*)d_in[5];
  P.Wi = (const float*)d_in[6];  P.bi = (const float*)d_in[7];
  P.Wg = (const float*)d_in[8];  P.bg = (const float*)d_in[9];
  P.Wsi = (const float*)d_in[10]; P.bsi = (const float*)d_in[11];
  P.Wsg = (const float*)d_in[12]; P.bsg = (const float*)d_in[13];
  P.eWih = (const float*)d_in[14]; P.eWhh = (const float*)d_in[15];
  P.ebih = (const float*)d_in[16]; P.ebhh = (const float*)d_in[17];
  P.dWih0 = (const float*)d_in[18]; P.dWhh0 = (const float*)d_in[19];
  P.dbih0 = (const float*)d_in[20]; P.dbhh0 = (const float*)d_in[21];
  P.dWih1 = (const float*)d_in[22]; P.dWhh1 = (const float*)d_in[23];
  P.dbih1 = (const float*)d_in[24]; P.dbhh1 = (const float*)d_in[25];
  P.fcW = (const float*)d_in[26]; P.fcb = (const float*)d_in[27];
  P.out = (float*)d_out;

  char* base = (char*)d_ws;
  size_t off = 0;
  auto take = [&](size_t bytes) -> char* {
    char* r = base + off;
    off = (off + bytes + 255) & ~(size_t)255;
    return r;
  };
  P.ctrl    = (unsigned*)take(4096);
  P.wpea_h  = (unsigned short*)take((size_t)294912 * 2);
  P.wpea_l  = (unsigned short*)take((size_t)294912 * 2);
  P.wpenc_h = (unsigned short*)take((size_t)524288 * 2);
  P.wpenc_l = (unsigned short*)take((size_t)524288 * 2);
  P.wpd0_h  = (unsigned short*)take((size_t)262144 * 2);
  P.wpd0_l  = (unsigned short*)take((size_t)262144 * 2);
  P.wpd1_h  = (unsigned short*)take((size_t)524288 * 2);
  P.wpd1_l  = (unsigned short*)take((size_t)524288 * 2);
  P.xp_h    = (unsigned short*)take((size_t)2990080 * 2);
  P.xp_l    = (unsigned short*)take((size_t)2990080 * 2);
  P.si_v    = (float*)take((size_t)65536 * 4);
  P.sg_v    = (float*)take((size_t)65536 * 4);
  P.cbea    = (float*)take(4096);
  P.cbenc   = (float*)take(4096);
  P.cbd0    = (float*)take(4096);
  P.cbd1    = (float*)take(4096);
  P.w0v     = (float*)take(4096);
  P.fcw     = (float*)take(1024);
  P.pred    = (float*)take((size_t)6144 * 4);
  P.henc    = (unsigned short*)take((size_t)2 * 131072 * 2);
  P.hA      = (unsigned short*)take((size_t)2 * 131072 * 2);
  P.hB      = (unsigned short*)take((size_t)2 * 131072 * 2);
  P.hseq    = (unsigned short*)take((size_t)365 * 131072 * 2);

  hipMemsetAsync(d_ws, 0, 4096, stream);
  hipLaunchKernelGGL(ea_lstm_fused, dim3(64), dim3(256), 0, stream, P);
}